// Round 1
// baseline (6483.884 us; speedup 1.0000x reference)
//
#include <hip/hip_runtime.h>
#include <stdint.h>

#define T_STEPS 2048
#define BATCH   16
#define DIM     1024

typedef float  f32x4  __attribute__((ext_vector_type(4)));
typedef __bf16 bf16x8 __attribute__((ext_vector_type(8)));

// ---------------------------------------------------------------------------
// prep: h[0] = h0, init tagged exchange buffers (tag 0 = h0, sentinel in buf1)
// ---------------------------------------------------------------------------
__global__ void prep_kernel(const float* __restrict__ h0,
                            float* __restrict__ hout,
                            unsigned long long* __restrict__ hX) {
  int i = blockIdx.x * blockDim.x + threadIdx.x;
  if (i < BATCH * DIM) {
    float v = h0[i];
    hout[i] = v;
    hX[i] = (unsigned long long)__float_as_uint(v);   // tag 0, value h0
    hX[BATCH * DIM + i] = 0xFFFFFFFF00000000ull;      // sentinel tag
  }
}

// ---------------------------------------------------------------------------
// xp = x @ W_x^T + b   (M=32768, N=1024, K=1024), bf16 MFMA, 128x128 tile
// Both operands are [rows][K] row-major (B^T form) -> K-contiguous frags.
// ---------------------------------------------------------------------------
__global__ __launch_bounds__(256)
void xp_gemm(const float* __restrict__ X, const float* __restrict__ W,
             const float* __restrict__ Bv, float* __restrict__ XP) {
  __shared__ __bf16 As[128 * 64];
  __shared__ __bf16 Bs[128 * 64];
  const int tid = threadIdx.x;
  const int bm = blockIdx.x & 255;   // 256 M-tiles
  const int bn = blockIdx.x >> 8;    // 8 N-tiles
  const int w = tid >> 6, l = tid & 63;
  const int wr = w >> 1, wc = w & 1;         // wave quadrant (64x64)
  const int sr = tid >> 1, sh = tid & 1;     // staging row / half

  const float* xrow = X + (size_t)(bm * 128 + sr) * DIM + sh * 32;
  const float* wrow = W + (size_t)(bn * 128 + sr) * DIM + sh * 32;
  char* AsB = (char*)As;
  char* BsB = (char*)Bs;
  const int swr  = sr * 128;
  const int swzs = (sr & 7) << 4;

  f32x4 acc[4][4];
  const f32x4 z4 = {0.f, 0.f, 0.f, 0.f};
#pragma unroll
  for (int i = 0; i < 4; ++i)
#pragma unroll
    for (int j = 0; j < 4; ++j) acc[i][j] = z4;

  for (int kt = 0; kt < 16; ++kt) {
    // stage: f32 -> bf16 into XOR-swizzled LDS (16B-block swizzle, G4)
#pragma unroll
    for (int j = 0; j < 8; ++j) {
      f32x4 a  = *(const f32x4*)(xrow + kt * 64 + 4 * j);
      f32x4 bv = *(const f32x4*)(wrow + kt * 64 + 4 * j);
      union { __bf16 h[4]; unsigned long long u; } pa, pb;
#pragma unroll
      for (int q = 0; q < 4; ++q) { pa.h[q] = (__bf16)a[q]; pb.h[q] = (__bf16)bv[q]; }
      int c2  = (sh * 32 + 4 * j) * 2;       // byte col within 128B row
      int off = swr + (c2 ^ swzs);
      *(unsigned long long*)(AsB + off) = pa.u;
      *(unsigned long long*)(BsB + off) = pb.u;
    }
    __syncthreads();
#pragma unroll
    for (int ks = 0; ks < 2; ++ks) {
      bf16x8 afr[4], bfr[4];
#pragma unroll
      for (int mi = 0; mi < 4; ++mi) {
        int row = wr * 64 + mi * 16 + (l & 15);
        int c2  = ks * 64 + (l >> 4) * 16;
        afr[mi] = *(const bf16x8*)(AsB + row * 128 + (c2 ^ ((row & 7) << 4)));
      }
#pragma unroll
      for (int ni = 0; ni < 4; ++ni) {
        int row = wc * 64 + ni * 16 + (l & 15);
        int c2  = ks * 64 + (l >> 4) * 16;
        bfr[ni] = *(const bf16x8*)(BsB + row * 128 + (c2 ^ ((row & 7) << 4)));
      }
#pragma unroll
      for (int mi = 0; mi < 4; ++mi)
#pragma unroll
        for (int ni = 0; ni < 4; ++ni)
          acc[mi][ni] = __builtin_amdgcn_mfma_f32_16x16x32_bf16(
              afr[mi], bfr[ni], acc[mi][ni], 0, 0, 0);
    }
    __syncthreads();
  }
  // epilogue: C/D layout col=lane&15, row=(lane>>4)*4+reg (m89-verified)
  const int colb = bn * 128 + wc * 64 + (l & 15);
#pragma unroll
  for (int ni = 0; ni < 4; ++ni) {
    int col = colb + ni * 16;
    float bb = Bv[col];
#pragma unroll
    for (int mi = 0; mi < 4; ++mi) {
      int row = bm * 128 + wr * 64 + mi * 16 + ((l >> 4) << 2);
#pragma unroll
      for (int r = 0; r < 4; ++r)
        XP[(size_t)(row + r) * DIM + col] = acc[mi][ni][r] + bb;
    }
  }
}

// ---------------------------------------------------------------------------
// recurrence: 16 batches x 16 WGs (64 rows each), W_h slice in registers.
// Tagged u64 atomics (data carries step tag) = 1 LLC round trip per step.
// ---------------------------------------------------------------------------
__global__ __launch_bounds__(1024, 4)
void rnn_kernel(const float* __restrict__ Wh,
                const float* __restrict__ Z,
                const float* __restrict__ gz,
                const float* __restrict__ gh,
                const float* __restrict__ bg,
                float* __restrict__ out,    // holds xp, overwritten with out
                float* __restrict__ hout,   // [T+1][B][D]
                unsigned long long* __restrict__ hX) {
  __shared__ float hb[2][1024];
  const int b   = blockIdx.x >> 4;
  const int s   = blockIdx.x & 15;
  const int tid = threadIdx.x;
  const int w   = tid >> 6;
  const int l   = tid & 63;
  const int r0  = s * 64;
  const int myrow  = r0 + w * 4 + (l & 3);
  const bool writer = (l < 4);

  // W_h slice -> registers: wave w owns rows r0+4w..+3, lane l owns K [16l,16l+16)
  f32x4 W4[4][4];
  {
    const f32x4* WhV = (const f32x4*)Wh;
#pragma unroll
    for (int r4 = 0; r4 < 4; ++r4) {
      size_t base = (size_t)(r0 + w * 4 + r4) * (DIM / 4) + l * 4;
#pragma unroll
      for (int jj = 0; jj < 4; ++jj) W4[r4][jj] = WhV[base + jj];
    }
  }

  float cgz = 0.f, cgh = 0.f, cbg = 0.f, xp_n = 0.f, z_n = 0.f;
  if (writer) {
    cgz = gz[myrow]; cgh = gh[myrow]; cbg = bg[myrow];
    xp_n = out[(size_t)b * DIM + myrow];   // xp[0,b,myrow]
    z_n  = Z[(size_t)b * DIM + myrow];
  }

  unsigned long long* hx0 = hX + (size_t)b * DIM;
  unsigned long long* hx1 = hX + (size_t)(BATCH + b) * DIM;
  const int swz_w = tid ^ (((tid >> 5) & 7) << 2);   // 16B-block LDS swizzle

  for (int t = 0; t < T_STEPS; ++t) {
    unsigned long long* src = (t & 1) ? hx1 : hx0;
    unsigned long long* dst = (t & 1) ? hx0 : hx1;
    // poll own value (tag == t)
    unsigned long long v;
    int spins = 0;
    do {
      v = __hip_atomic_load(&src[tid], __ATOMIC_RELAXED, __HIP_MEMORY_SCOPE_AGENT);
    } while ((unsigned)(v >> 32) != (unsigned)t && ++spins < 4096);
    hb[t & 1][swz_w] = __uint_as_float((unsigned)v);
    __syncthreads();
    // matvec: 64 FMA/thread from swizzled LDS (conflict-free b128)
    float acc0 = 0.f, acc1 = 0.f, acc2 = 0.f, acc3 = 0.f;
#pragma unroll
    for (int jj = 0; jj < 4; ++jj) {
      int word = ((l << 4) | (jj << 2)) ^ (((l >> 1) & 7) << 2);
      f32x4 h4 = *(const f32x4*)&hb[t & 1][word];
#pragma unroll
      for (int i = 0; i < 4; ++i) {
        acc0 = fmaf(W4[0][jj][i], h4[i], acc0);
        acc1 = fmaf(W4[1][jj][i], h4[i], acc1);
        acc2 = fmaf(W4[2][jj][i], h4[i], acc2);
        acc3 = fmaf(W4[3][jj][i], h4[i], acc3);
      }
    }
#pragma unroll
    for (int m = 32; m >= 1; m >>= 1) {
      acc0 += __shfl_xor(acc0, m);
      acc1 += __shfl_xor(acc1, m);
      acc2 += __shfl_xor(acc2, m);
      acc3 += __shfl_xor(acc3, m);
    }
    if (writer) {
      float accm = (l == 0) ? acc0 : (l == 1) ? acc1 : (l == 2) ? acc2 : acc3;
      float pre = accm + xp_n;
      float e2 = __expf(2.0f * pre);
      float hn = 1.0f - 2.0f / (e2 + 1.0f);          // tanh, overflow-safe
      unsigned long long pk = ((unsigned long long)(unsigned)(t + 1) << 32)
                            | (unsigned long long)__float_as_uint(hn);
      __hip_atomic_store(&dst[myrow], pk, __ATOMIC_RELAXED, __HIP_MEMORY_SCOPE_AGENT);
      hout[((size_t)(t + 1) * BATCH + b) * DIM + myrow] = hn;
      float y   = z_n * cgz + hn * cgh + cbg;
      float sig = 1.0f / (1.0f + __expf(-y));
      out[((size_t)t * BATCH + b) * DIM + myrow] = hn * (y * sig);
      if (t + 1 < T_STEPS) {   // prefetch next step's xp, z off the hot path
        xp_n = out[((size_t)(t + 1) * BATCH + b) * DIM + myrow];
        z_n  = Z[((size_t)(t + 1) * BATCH + b) * DIM + myrow];
      }
    }
  }
}

extern "C" void kernel_launch(void* const* d_in, const int* in_sizes, int n_in,
                              void* d_out, int out_size, void* d_ws, size_t ws_size,
                              hipStream_t stream) {
  const float* x    = (const float*)d_in[0];
  const float* z    = (const float*)d_in[1];
  const float* h0   = (const float*)d_in[2];
  const float* Wx   = (const float*)d_in[3];
  const float* Wh   = (const float*)d_in[4];
  const float* bias = (const float*)d_in[5];
  const float* gz   = (const float*)d_in[6];
  const float* gh   = (const float*)d_in[7];
  const float* bg   = (const float*)d_in[8];

  float* out  = (float*)d_out;
  float* hout = out + (size_t)T_STEPS * BATCH * DIM;
  unsigned long long* hX = (unsigned long long*)d_ws;  // 2*B*D*8 = 256 KB

  prep_kernel<<<dim3(64), dim3(256), 0, stream>>>(h0, hout, hX);
  xp_gemm<<<dim3(2048), dim3(256), 0, stream>>>(x, Wx, bias, out);
  rnn_kernel<<<dim3(256), dim3(1024), 0, stream>>>(Wh, z, gz, gh, bg, out, hout, hX);
}

// Round 3
// 5546.609 us; speedup vs baseline: 1.1690x; 1.1690x over previous
//
#include <hip/hip_runtime.h>
#include <stdint.h>

#define T_STEPS 2048
#define BATCH   16
#define DIM     1024

typedef float    f32x4 __attribute__((ext_vector_type(4)));
typedef float    f32x2 __attribute__((ext_vector_type(2)));
typedef unsigned u32x4 __attribute__((ext_vector_type(4)));
typedef __bf16   bf16x8 __attribute__((ext_vector_type(8)));

// ---------------------------------------------------------------------------
// prep: h[0] = h0, init tagged exchange buffers (tag 0 = h0, sentinel in buf1)
// ---------------------------------------------------------------------------
__global__ void prep_kernel(const float* __restrict__ h0,
                            float* __restrict__ hout,
                            unsigned long long* __restrict__ hX) {
  int i = blockIdx.x * blockDim.x + threadIdx.x;
  if (i < BATCH * DIM) {
    float v = h0[i];
    hout[i] = v;
    hX[i] = (unsigned long long)__float_as_uint(v);   // tag 0 | h0
    hX[BATCH * DIM + i] = 0xFFFFFFFF00000000ull;      // sentinel tag
  }
}

// ---------------------------------------------------------------------------
// xp = x @ W_x^T + b  (R1-proven, ~230us total with prep)
// ---------------------------------------------------------------------------
__global__ __launch_bounds__(256)
void xp_gemm(const float* __restrict__ X, const float* __restrict__ W,
             const float* __restrict__ Bv, float* __restrict__ XP) {
  __shared__ __bf16 As[128 * 64];
  __shared__ __bf16 Bs[128 * 64];
  const int tid = threadIdx.x;
  const int bm = blockIdx.x & 255;
  const int bn = blockIdx.x >> 8;
  const int w = tid >> 6, l = tid & 63;
  const int wr = w >> 1, wc = w & 1;
  const int sr = tid >> 1, sh = tid & 1;

  const float* xrow = X + (size_t)(bm * 128 + sr) * DIM + sh * 32;
  const float* wrow = W + (size_t)(bn * 128 + sr) * DIM + sh * 32;
  char* AsB = (char*)As;
  char* BsB = (char*)Bs;
  const int swr  = sr * 128;
  const int swzs = (sr & 7) << 4;

  f32x4 acc[4][4];
  const f32x4 z4 = {0.f, 0.f, 0.f, 0.f};
#pragma unroll
  for (int i = 0; i < 4; ++i)
#pragma unroll
    for (int j = 0; j < 4; ++j) acc[i][j] = z4;

  for (int kt = 0; kt < 16; ++kt) {
#pragma unroll
    for (int j = 0; j < 8; ++j) {
      f32x4 a  = *(const f32x4*)(xrow + kt * 64 + 4 * j);
      f32x4 bv = *(const f32x4*)(wrow + kt * 64 + 4 * j);
      union { __bf16 h[4]; unsigned long long u; } pa, pb;
#pragma unroll
      for (int q = 0; q < 4; ++q) { pa.h[q] = (__bf16)a[q]; pb.h[q] = (__bf16)bv[q]; }
      int c2  = (sh * 32 + 4 * j) * 2;
      int off = swr + (c2 ^ swzs);
      *(unsigned long long*)(AsB + off) = pa.u;
      *(unsigned long long*)(BsB + off) = pb.u;
    }
    __syncthreads();
#pragma unroll
    for (int ks = 0; ks < 2; ++ks) {
      bf16x8 afr[4], bfr[4];
#pragma unroll
      for (int mi = 0; mi < 4; ++mi) {
        int row = wr * 64 + mi * 16 + (l & 15);
        int c2  = ks * 64 + (l >> 4) * 16;
        afr[mi] = *(const bf16x8*)(AsB + row * 128 + (c2 ^ ((row & 7) << 4)));
      }
#pragma unroll
      for (int ni = 0; ni < 4; ++ni) {
        int row = wc * 64 + ni * 16 + (l & 15);
        int c2  = ks * 64 + (l >> 4) * 16;
        bfr[ni] = *(const bf16x8*)(BsB + row * 128 + (c2 ^ ((row & 7) << 4)));
      }
#pragma unroll
      for (int mi = 0; mi < 4; ++mi)
#pragma unroll
        for (int ni = 0; ni < 4; ++ni)
          acc[mi][ni] = __builtin_amdgcn_mfma_f32_16x16x32_bf16(
              afr[mi], bfr[ni], acc[mi][ni], 0, 0, 0);
    }
    __syncthreads();
  }
  const int colb = bn * 128 + wc * 64 + (l & 15);
#pragma unroll
  for (int ni = 0; ni < 4; ++ni) {
    int col = colb + ni * 16;
    float bb = Bv[col];
#pragma unroll
    for (int mi = 0; mi < 4; ++mi) {
      int row = bm * 128 + wr * 64 + mi * 16 + ((l >> 4) << 2);
#pragma unroll
      for (int r = 0; r < 4; ++r)
        XP[(size_t)(row + r) * DIM + col] = acc[mi][ni][r] + bb;
    }
  }
}

// ---------------------------------------------------------------------------
// recurrence: 16 batches x 16 WGs, tagged sc1 exchange (R1-proven protocol),
// but ONE detector wave per WG: wave 0 polls all 1024 tagged cols in a single
// 8x dwordx4 round (coalesced), scatters values to LDS, one barrier releases
// the WG. Removes the max-of-16-waves detect jitter of R1.
// ---------------------------------------------------------------------------
__global__ __launch_bounds__(1024, 4)
void rnn_kernel(const float* __restrict__ Wh, const float* __restrict__ Z,
                const float* __restrict__ gz, const float* __restrict__ gh,
                const float* __restrict__ bg,
                float* __restrict__ out,    // holds xp, overwritten with out
                float* __restrict__ hout,   // [T+1][B][D]
                unsigned long long* __restrict__ hX) {
  __shared__ float hb[2][1024];
  const int tid = threadIdx.x;
  const int w   = tid >> 6;
  const int l   = tid & 63;
  const int b   = blockIdx.x >> 4;
  const int s   = blockIdx.x & 15;
  const int r0  = s * 64;
  const int myrow  = r0 + w * 4 + (l & 3);
  const bool writer = (l < 4);

  // W_h slice -> registers: wave w owns rows r0+4w..+3, lane l owns K [16l,16l+16)
  f32x4 W4[4][4];
  {
    const f32x4* WhV = (const f32x4*)Wh;
#pragma unroll
    for (int r4 = 0; r4 < 4; ++r4) {
      size_t base = (size_t)(r0 + w * 4 + r4) * (DIM / 4) + l * 4;
#pragma unroll
      for (int jj = 0; jj < 4; ++jj) W4[r4][jj] = WhV[base + jj];
    }
  }

  float cgz = 0.f, cgh = 0.f, cbg = 0.f, xp_n = 0.f, z_n = 0.f;
  if (writer) {
    cgz = gz[myrow]; cgh = gh[myrow]; cbg = bg[myrow];
    xp_n = out[(size_t)b * DIM + myrow];   // xp[0,b,myrow]
    z_n  = Z[(size_t)b * DIM + myrow];
  }

  unsigned long long* hx0 = hX + (size_t)b * DIM;
  unsigned long long* hx1 = hX + (size_t)(BATCH + b) * DIM;

  for (int t = 0; t < T_STEPS; ++t) {
    unsigned long long* src = (t & 1) ? hx1 : hx0;
    unsigned long long* dst = (t & 1) ? hx0 : hx1;

    if (w == 0) {
      // wave 0: poll the whole batch vector (1024 tagged u64 = 8KB).
      // lane covers cols {2(l+64j)}: instr j loads 16B at byte 1024j+16l.
      const char* a0 = (const char*)src + 16 * l;
      const char* a1 = a0 + 4096;
      const unsigned tt = (unsigned)t;
      u32x4 q0, q1, q2, q3, q4, q5, q6, q7;
      int spins = 0;
      for (;;) {
        asm volatile(
            "global_load_dwordx4 %[q0], %[a0], off sc1\n\t"
            "global_load_dwordx4 %[q1], %[a0], off offset:1024 sc1\n\t"
            "global_load_dwordx4 %[q2], %[a0], off offset:2048 sc1\n\t"
            "global_load_dwordx4 %[q3], %[a0], off offset:3072 sc1\n\t"
            "global_load_dwordx4 %[q4], %[a1], off sc1\n\t"
            "global_load_dwordx4 %[q5], %[a1], off offset:1024 sc1\n\t"
            "global_load_dwordx4 %[q6], %[a1], off offset:2048 sc1\n\t"
            "global_load_dwordx4 %[q7], %[a1], off offset:3072 sc1\n\t"
            "s_waitcnt vmcnt(0)"
            : [q0]"=v"(q0), [q1]"=v"(q1), [q2]"=v"(q2), [q3]"=v"(q3),
              [q4]"=v"(q4), [q5]"=v"(q5), [q6]"=v"(q6), [q7]"=v"(q7)
            : [a0]"v"(a0), [a1]"v"(a1)
            : "memory");
        int ok = (q0.y == tt) & (q0.w == tt) & (q1.y == tt) & (q1.w == tt) &
                 (q2.y == tt) & (q2.w == tt) & (q3.y == tt) & (q3.w == tt) &
                 (q4.y == tt) & (q4.w == tt) & (q5.y == tt) & (q5.w == tt) &
                 (q6.y == tt) & (q6.w == tt) & (q7.y == tt) & (q7.w == tt);
        if (__all(ok)) break;
        if (++spins >= (1 << 22)) break;            // safety valve
        __builtin_amdgcn_s_sleep(2);
      }
      // scatter values (cols 2(l+64j), 2(l+64j)+1) to XOR-swizzled LDS
#define SCAT(J, Q) { int w0 = 2 * l + 128 * J; w0 ^= ((w0 >> 5) & 7) << 2; \
      f32x2 p; p.x = __uint_as_float(Q.x); p.y = __uint_as_float(Q.z);      \
      *(f32x2*)&hb[t & 1][w0] = p; }
      SCAT(0, q0) SCAT(1, q1) SCAT(2, q2) SCAT(3, q3)
      SCAT(4, q4) SCAT(5, q5) SCAT(6, q6) SCAT(7, q7)
#undef SCAT
    }
    __syncthreads();

    // matvec: 64 FMA/thread from swizzled LDS (conflict-free b128)
    float acc0 = 0.f, acc1 = 0.f, acc2 = 0.f, acc3 = 0.f;
#pragma unroll
    for (int jj = 0; jj < 4; ++jj) {
      int word = ((l << 4) | (jj << 2)) ^ (((l >> 1) & 7) << 2);
      f32x4 h4 = *(const f32x4*)&hb[t & 1][word];
#pragma unroll
      for (int i = 0; i < 4; ++i) {
        acc0 = fmaf(W4[0][jj][i], h4[i], acc0);
        acc1 = fmaf(W4[1][jj][i], h4[i], acc1);
        acc2 = fmaf(W4[2][jj][i], h4[i], acc2);
        acc3 = fmaf(W4[3][jj][i], h4[i], acc3);
      }
    }
    // 7-shuffle multi-reduce: lane l ends with full 64-lane sum of acc_{l&3}
    float w01 = (l & 1) ? acc0 : acc1;
    float v01 = ((l & 1) ? acc1 : acc0) + __shfl_xor(w01, 1);
    float w23 = (l & 1) ? acc2 : acc3;
    float v23 = ((l & 1) ? acc3 : acc2) + __shfl_xor(w23, 1);
    float wv  = (l & 2) ? v01 : v23;
    float vv  = ((l & 2) ? v23 : v01) + __shfl_xor(wv, 2);
    vv += __shfl_xor(vv, 4);
    vv += __shfl_xor(vv, 8);
    vv += __shfl_xor(vv, 16);
    vv += __shfl_xor(vv, 32);

    if (writer) {
      float pre = vv + xp_n;
      float e2 = __expf(2.0f * pre);
      float hn = 1.0f - 2.0f / (e2 + 1.0f);          // tanh, overflow-safe
      unsigned long long pk = ((unsigned long long)(unsigned)(t + 1) << 32)
                            | (unsigned long long)__float_as_uint(hn);
      __hip_atomic_store(&dst[myrow], pk, __ATOMIC_RELAXED, __HIP_MEMORY_SCOPE_AGENT);
      hout[((size_t)(t + 1) * BATCH + b) * DIM + myrow] = hn;
      float y   = z_n * cgz + hn * cgh + cbg;
      float sig = 1.0f / (1.0f + __expf(-y));
      out[((size_t)t * BATCH + b) * DIM + myrow] = hn * (y * sig);
      if (t + 1 < T_STEPS) {   // prefetch next step's xp, z off the hot path
        xp_n = out[((size_t)(t + 1) * BATCH + b) * DIM + myrow];
        z_n  = Z[((size_t)(t + 1) * BATCH + b) * DIM + myrow];
      }
    }
  }
}

extern "C" void kernel_launch(void* const* d_in, const int* in_sizes, int n_in,
                              void* d_out, int out_size, void* d_ws, size_t ws_size,
                              hipStream_t stream) {
  const float* x    = (const float*)d_in[0];
  const float* z    = (const float*)d_in[1];
  const float* h0   = (const float*)d_in[2];
  const float* Wx   = (const float*)d_in[3];
  const float* Wh   = (const float*)d_in[4];
  const float* bias = (const float*)d_in[5];
  const float* gz   = (const float*)d_in[6];
  const float* gh   = (const float*)d_in[7];
  const float* bg   = (const float*)d_in[8];

  float* out  = (float*)d_out;
  float* hout = out + (size_t)T_STEPS * BATCH * DIM;
  unsigned long long* hX = (unsigned long long*)d_ws;  // 2*B*D*8 = 256 KB

  prep_kernel<<<dim3(64), dim3(256), 0, stream>>>(h0, hout, hX);
  xp_gemm<<<dim3(2048), dim3(256), 0, stream>>>(x, Wx, bias, out);
  rnn_kernel<<<dim3(256), dim3(1024), 0, stream>>>(Wh, z, gz, gh, bg, out, hout, hX);
}